// Round 10
// baseline (27.682 us; speedup 1.0000x reference)
//
#include <hip/hip_runtime.h>

#define NK 16   // cluster centers
#define E  7    // f32x4 elems/thread: n4 = 12544*256, 12544 = 1792*7 -> 1792 blocks = 7/CU, all resident

typedef float  f32x4 __attribute__((ext_vector_type(4)));
typedef float  f32x2 __attribute__((ext_vector_type(2)));

// ws layout (floats): [0,512) lut | [512,528) cen | [528,784) den | [784,1040) r256 | [1040,1296) so
#define WS_LUT   0
#define WS_CEN   512
#define WS_DEN   528
#define WS_R256  784
#define WS_SO    1040

// Bit-exact replica of the reference's per-element assignment for ANY t:
// scan k ascending, strict <  -> first index wins ties (jnp.argmin semantics).
__device__ __forceinline__ float argmin16(float t, const float* cen) {
    float best = 3.4e38f;
    float bc = 0.0f;
#pragma unroll
    for (int k = 0; k < NK; ++k) {
        float d = fabsf(t - cen[k]);
        bool p = d < best;
        best = p ? d : best;
        bc   = p ? cen[k] : bc;
    }
    return bc;
}

// ---- Prep kernel: one 256-thread block fills ws with LUT + per-channel
// constants. Removes ALL argmin/divide prologue work from the main kernel.
__global__ __launch_bounds__(256) void lutfq_prep(
    const float* __restrict__ scales,
    const float* __restrict__ centers,
    float*       __restrict__ ws)
{
    const int tid = threadIdx.x;
    float cen[NK];
#pragma unroll
    for (int k = 0; k < NK; ++k) cen[k] = rintf(centers[k]);  // round-half-to-even
    if (tid < NK) ws[WS_CEN + tid] = cen[tid];

    float s   = scales[tid];            // 256 channels == 256 threads
    float den = s + 1e-8f;              // ref's denominator
    ws[WS_DEN  + tid] = den;
    ws[WS_R256 + tid] = 256.0f / den;   // fast-path reciprocal (<=1 ulp on u2)
    ws[WS_SO   + tid] = s * 0.0078125f; // s/128, exact

    // 512-bucket LUT over u2 = 2t; integer centers -> decision midpoints are
    // half-integers = bucket edges -> constant on bucket interiors. Buckets
    // 0 / >=510 built at their LEFT edge (t=-128/127): provably never a
    // midpoint of distinct integer centers in [-128,127] -> the clip masses
    // are served exactly with no fallback.
    for (int ub = tid; ub < 512; ub += 256) {
        float t;
        if (ub == 0)        t = -128.0f;
        else if (ub >= 510) t = 127.0f;
        else                t = 0.5f * (float)(ub - 256) + 0.25f;
        ws[WS_LUT + ub] = argmin16(t, cen);
    }
}

// ---- Main kernel: 1792 blocks x 256 thr, 7 f32x4/thread, all resident at
// once (7 blocks/CU, 28 waves/CU under the 72-VGPR budget of bounds(256,7)).
// No per-block argmin prologue: tables stream from ws (L3-broadcast) to LDS.
__global__ __launch_bounds__(256, 7) void lutfq_main(
    const f32x4* __restrict__ x,
    const float* __restrict__ ws,
    f32x4*       __restrict__ out,
    int n4)
{
    __shared__ float s_lut[512];
    __shared__ float s_cd[272];   // [0,16) cen | [16,272) den

    const int tid = threadIdx.x;

    // Small table loads FIRST (oldest in vmcnt FIFO -> LDS fill + barrier do
    // not wait on the 7 HBM streaming loads issued after them).
    f32x2 lutv = *reinterpret_cast<const f32x2*>(&ws[WS_LUT + 2 * tid]);
    float cdv  = ws[WS_CEN + tid];                       // cen(16)+den(240)
    float cdv2 = (tid < NK) ? ws[WS_CEN + 256 + tid] : 0.f;  // den tail (16)
    const int c4 = (tid & 63) * 4;  // per-thread channels: i === tid (mod 64)
    f32x4 r256 = *reinterpret_cast<const f32x4*>(&ws[WS_R256 + c4]);
    f32x4 so   = *reinterpret_cast<const f32x4*>(&ws[WS_SO   + c4]);

    // The 7 streaming loads: issued back-to-back, 7-deep MLP per wave.
    const int i0 = blockIdx.x * (256 * E) + tid;
    f32x4 v[E];
#pragma unroll
    for (int u = 0; u < E; ++u) {
        int i = i0 + u * 256;
        v[u] = (i < n4) ? x[i] : f32x4{0.f, 0.f, 0.f, 0.f};
    }

    *reinterpret_cast<f32x2*>(&s_lut[2 * tid]) = lutv;
    s_cd[tid] = cdv;
    if (tid < NK) s_cd[256 + tid] = cdv2;
    __syncthreads();

#pragma unroll
    for (int u = 0; u < E; ++u) {
        int i = i0 + u * 256;
        f32x4 xv = v[u];
        f32x4 r;
#pragma unroll
        for (int j = 0; j < 4; ++j) {
            // u2 = 2 * clip(x/(s+eps)*128, -128, 127) as one mul + clamp.
            float u2 = xv[j] * r256[j];
            u2 = fminf(fmaxf(u2, -256.0f), 254.0f);

            float fl   = floorf(u2);      // exact
            float frac = u2 - fl;
            int   ub   = (int)fl + 256;   // 0..510

            float c = s_lut[ub];

            // Edge band (reciprocal's <=2^-15 error + ref's rounded-distance
            // tie band), minus the provably-safe clamp rails: replay exact
            // ref arithmetic from LDS tables. ~5e-4 of elements, exec-masked.
            bool band = (frac < 0x1p-12f) | (frac > 1.0f - 0x1p-12f);
            bool rail = (u2 == -256.0f) | (u2 == 254.0f);
            if (band && !rail) {
                float den = s_cd[16 + c4 + j];
                float t = (xv[j] / den) * 128.0f;
                t = fminf(fmaxf(t, -128.0f), 127.0f);
                c = argmin16(t, &s_cd[0]);              // bit-exact ref replay
            }
            r[j] = c * so[j];   // c*(s/128) == (c/128)*s bit-exactly
        }
        if (i < n4) out[i] = r;
    }
}

extern "C" void kernel_launch(void* const* d_in, const int* in_sizes, int n_in,
                              void* d_out, int out_size, void* d_ws, size_t ws_size,
                              hipStream_t stream) {
    const float* x       = (const float*)d_in[0];
    const float* scales  = (const float*)d_in[1];
    const float* centers = (const float*)d_in[2];
    float* out = (float*)d_out;
    float* ws  = (float*)d_ws;

    int n4 = out_size / 4;                          // 3,211,264 here
    int per_block = 256 * E;                        // 1792 elements/block
    int blocks = (n4 + per_block - 1) / per_block;  // 1792 -> exactly 7 WGs/CU

    lutfq_prep<<<1, 256, 0, stream>>>(scales, centers, ws);
    lutfq_main<<<blocks, 256, 0, stream>>>(
        (const f32x4*)x, ws, (f32x4*)out, n4);
}

// Round 11
// 21.226 us; speedup vs baseline: 1.3042x; 1.3042x over previous
//
#include <hip/hip_runtime.h>

#define NK 16   // cluster centers
#define E  2    // f32x4 elements per thread (n4 = 6272 * 512 exactly)

typedef float f32x4 __attribute__((ext_vector_type(4)));

// Bit-exact replica of the reference's per-element assignment for ANY t:
// scan k ascending, strict <  -> first index wins ties (jnp.argmin semantics).
__device__ __forceinline__ float argmin16(float t, const float* cen) {
    float best = 3.4e38f;
    float bc = 0.0f;
#pragma unroll
    for (int k = 0; k < NK; ++k) {
        float d = fabsf(t - cen[k]);
        bool p = d < best;
        best = p ? d : best;
        bc   = p ? cen[k] : bc;
    }
    return bc;
}

// Best-known configuration (R8): single launch, E=2, 6272 blocks, early loads,
// no min-waves bound (a (256,8)/(256,7) cap spills prefetch regs to scratch).
__global__ __launch_bounds__(256) void lutfq_kernel(
    const f32x4* __restrict__ x,
    const float* __restrict__ scales,
    const float* __restrict__ centers,
    f32x4*       __restrict__ out,
    int n4)
{
    __shared__ float s_lut[512];  // bucket -> center over u2 = 2t

    const int tid = threadIdx.x;
    // Block-contiguous: block owns [blockIdx*512, blockIdx*512+512).
    const int i0 = blockIdx.x * (256 * E) + tid;
    const int i1 = i0 + 256;

    // ---- Issue both streaming loads FIRST; the whole prologue below (rint,
    // scale math, LUT build) executes while they're in flight.
    f32x4 v0 = {0.f, 0.f, 0.f, 0.f}, v1 = {0.f, 0.f, 0.f, 0.f};
    if (i0 < n4) v0 = x[i0];
    if (i1 < n4) v1 = x[i1];

    // Rounded centers in (wave-uniform) registers.
    float cen[NK];
#pragma unroll
    for (int k = 0; k < NK; ++k) cen[k] = rintf(centers[k]);  // round-half-to-even

    // Per-thread channels are invariant: i0,i1 mod 64 == tid mod 64
    // (512 and 256 are multiples of 64). Load the 4 owned scales once.
    const int c4 = (tid & 63) * 4;
    const f32x4 sv = *reinterpret_cast<const f32x4*>(&scales[c4]);
    float den[4], r256[4], so[4];
#pragma unroll
    for (int j = 0; j < 4; ++j) {
        den[j]  = sv[j] + 1e-8f;        // ref's denominator
        r256[j] = 256.0f / den[j];      // fast-path reciprocal (<=1 ulp on u2)
        so[j]   = sv[j] * 0.0078125f;   // s/128, exact
    }

    // 512-bucket LUT over u2 = 2t; integer centers -> decision midpoints are
    // half-integers = bucket edges -> constant on bucket interiors. Buckets
    // 0 / >=510 built at their LEFT edge (t=-128/127): provably never a
    // midpoint of distinct integer centers in [-128,127] -> clip masses are
    // exact with no fallback.
    for (int ub = tid; ub < 512; ub += 256) {
        float t;
        if (ub == 0)        t = -128.0f;
        else if (ub >= 510) t = 127.0f;
        else                t = 0.5f * (float)(ub - 256) + 0.25f;
        s_lut[ub] = argmin16(t, cen);
    }
    __syncthreads();

    auto process = [&](f32x4 xv) -> f32x4 {
        f32x4 r;
#pragma unroll
        for (int j = 0; j < 4; ++j) {
            // u2 = 2 * clip(x/(s+eps)*128, -128, 127) as one mul + clamp.
            float u2 = xv[j] * r256[j];
            u2 = fminf(fmaxf(u2, -256.0f), 254.0f);

            float fl   = floorf(u2);      // exact
            float frac = u2 - fl;
            int   ub   = (int)fl + 256;   // 0..510

            float c = s_lut[ub];

            // Edge band (reciprocal's <=2^-15 error + ref's rounded-distance
            // tie band), minus the provably-safe clamp rails: replay exact
            // ref arithmetic. ~5e-4 of elements, exec-masked.
            bool band = (frac < 0x1p-12f) | (frac > 1.0f - 0x1p-12f);
            bool rail = (u2 == -256.0f) | (u2 == 254.0f);
            if (band && !rail) {
                float t = (xv[j] / den[j]) * 128.0f;
                t = fminf(fmaxf(t, -128.0f), 127.0f);
                c = argmin16(t, cen);                   // bit-exact ref replay
            }
            r[j] = c * so[j];   // c*(s/128) == (c/128)*s bit-exactly
        }
        return r;
    };

    f32x4 r0 = process(v0);
    f32x4 r1 = process(v1);
    if (i0 < n4) out[i0] = r0;
    if (i1 < n4) out[i1] = r1;
}

extern "C" void kernel_launch(void* const* d_in, const int* in_sizes, int n_in,
                              void* d_out, int out_size, void* d_ws, size_t ws_size,
                              hipStream_t stream) {
    const float* x       = (const float*)d_in[0];
    const float* scales  = (const float*)d_in[1];
    const float* centers = (const float*)d_in[2];
    float* out = (float*)d_out;

    int n4 = out_size / 4;                      // 3,211,264 here
    int per_block = 256 * E;                    // 512
    int blocks = (n4 + per_block - 1) / per_block;  // 6272: 3x backfill depth

    lutfq_kernel<<<blocks, 256, 0, stream>>>(
        (const f32x4*)x, scales, centers, (f32x4*)out, n4);
}